// Round 9
// baseline (107.346 us; speedup 1.0000x reference)
//
#include <hip/hip_runtime.h>
#include <hip/hip_bf16.h>

#define BB    262144
#define INF   256
#define HIDF  128
#define OUTF  15
#define NCAM  15
#define TM    128
#define MAXTILES (BB/TM + NCAM)   // 2063

typedef __attribute__((ext_vector_type(8))) short          bf16x8;
typedef __attribute__((ext_vector_type(4))) float          floatx4;
typedef __attribute__((ext_vector_type(4))) int            intx4;
typedef __attribute__((ext_vector_type(4))) unsigned int   uintx4;
typedef __attribute__((ext_vector_type(8))) unsigned short ushortx8;

__device__ __forceinline__ unsigned short f2bf1(float a){
  unsigned int u = __builtin_bit_cast(unsigned int, a);
  u += 0x7fffu + ((u >> 16) & 1u);          // round-to-nearest-even
  return (unsigned short)(u >> 16);
}
__device__ __forceinline__ unsigned int f2bf2(float a, float b){
  return (unsigned int)f2bf1(a) | ((unsigned int)f2bf1(b) << 16);
}

// ---------- fused prepack + histogram (counts/scatterOfs pre-zeroed by memset) ----------
__global__ void k_prephist(const float* __restrict__ W1, const float* __restrict__ W2,
                           const int* __restrict__ cam,
                           unsigned short* __restrict__ W1p, unsigned short* __restrict__ W2p,
                           int* __restrict__ counts){
  int bid = blockIdx.x, tid = threadIdx.x;
  if (bid < 240){
    int t = bid * 256 + tid;
    int l  = t & 63;
    int kf = (t >> 6) & 7;
    int nf = (t >> 9) & 7;
    int c  = t >> 12;
    int col = nf*16 + (l & 15);
    int k0  = kf*32 + (l >> 4)*8;
    ushortx8 v;
    #pragma unroll
    for (int j = 0; j < 8; ++j)
      v[j] = f2bf1(W1[((size_t)c*INF + k0 + j)*HIDF + col]);
    *reinterpret_cast<ushortx8*>(W1p + (size_t)t*8) = v;
  } else if (bid < 255){
    int c  = bid - 240;
    int l  = tid & 63;
    int kf = tid >> 6;            // 0..3
    int col = l & 15;
    int k0  = kf*32 + (l >> 4)*8;
    ushortx8 v;
    #pragma unroll
    for (int j = 0; j < 8; ++j){
      float f = (col < OUTF) ? W2[((size_t)c*HIDF + k0 + j)*OUTF + col] : 0.0f;
      v[j] = f2bf1(f);
    }
    *reinterpret_cast<ushortx8*>(W2p + ((size_t)(c*4 + kf)*64 + l)*8) = v;
  } else if (bid >= 256){
    __shared__ int lc[NCAM];
    if (tid < NCAM) lc[tid] = 0;
    __syncthreads();
    intx4 v = *reinterpret_cast<const intx4*>(cam + (size_t)((bid-256)*256 + tid)*4);
    atomicAdd(&lc[v[0]], 1); atomicAdd(&lc[v[1]], 1);
    atomicAdd(&lc[v[2]], 1); atomicAdd(&lc[v[3]], 1);
    __syncthreads();
    if (tid < NCAM && lc[tid]) atomicAdd(&counts[tid], lc[tid]);
  }
}

// ---------- scatter ----------
__global__ void k_scatter(const int* __restrict__ cam, const int* __restrict__ counts,
                          int* __restrict__ scatterOfs, int* __restrict__ idx){
  __shared__ int lc[NCAM];
  __shared__ int loff[NCAM];
  __shared__ int base[NCAM];
  int t = threadIdx.x;
  if (t < NCAM) lc[t] = 0;
  __syncthreads();
  int start = blockIdx.x * 4096;
  int camr[16], lpos[16];
  #pragma unroll
  for (int j = 0; j < 16; ++j){
    int i = start + j*256 + t;
    camr[j] = cam[i];
    lpos[j] = atomicAdd(&lc[camr[j]], 1);
  }
  __syncthreads();
  if (t == 0){
    int s = 0;
    #pragma unroll
    for (int c = 0; c < NCAM; ++c){ loff[c] = s; s += counts[c]; }
  }
  __syncthreads();
  if (t < NCAM) base[t] = loff[t] + atomicAdd(&scatterOfs[t], lc[t]);
  __syncthreads();
  #pragma unroll
  for (int j = 0; j < 16; ++j)
    idx[base[camr[j]] + lpos[j]] = start + j*256 + t;
}

// ---------- main fused MLP: barrier-free per-wave pipeline ----------
// LDS (128.5 KB, 1 block/CU):
//   [0,64K)    W1s — staged W1p[c], read via lgkm queue (decoupled from vmcnt)
//   [64K,128K) A eighth-buffers: 4 bufs x 16KB; per-wave slice 4KB (wave-private!)
//              -> no __syncthreads needed in the K-loop; counted vmcnt only.
//   hbuf aliases A-buf 0/1 wave slices after the K-loop (also wave-private).
__global__ __launch_bounds__(256, 1) void k_mlp(
    const float* __restrict__ x, const int* __restrict__ idx,
    const int* __restrict__ counts,
    const unsigned short* __restrict__ W1p, const unsigned short* __restrict__ W2p,
    const float* __restrict__ b1, const float* __restrict__ b2,
    float* __restrict__ out)
{
  __shared__ __align__(16) char smem[131072 + 512];
  int* sidx = reinterpret_cast<int*>(smem + 131072);
  char* Ab = smem + 65536;

  int bid = blockIdx.x;
  int c = -1, segStart = 0, rowStart = 0, rows = 0;
  {
    int cum = 0, rcum = 0;
    #pragma unroll 1
    for (int cc = 0; cc < NCAM; ++cc){
      int n  = counts[cc];
      int nt = (n + TM - 1) / TM;
      if (c < 0 && bid < cum + nt){
        c = cc;
        rowStart = (bid - cum) * TM;
        segStart = rcum;
        rows = n - rowStart; if (rows > TM) rows = TM;
      }
      cum += nt; rcum += n;
    }
  }
  if (c < 0) return;

  int t = threadIdx.x;
  int wave = t >> 6, lane = t & 63;

  // prologue: stage W1p[c] (64KB) into W1s, linear
  {
    const char* gsrc = reinterpret_cast<const char*>(W1p + (size_t)c*32768);
    #pragma unroll
    for (int i = 0; i < 16; ++i){
      int ci = i*4 + wave;
      __builtin_amdgcn_global_load_lds(
        (const __attribute__((address_space(1))) unsigned int*)(gsrc + ci*1024 + lane*16),
        (__attribute__((address_space(3))) unsigned int*)(smem + ci*1024),
        16, 0, 0);
    }
  }
  if (t < TM){
    int r = (t < rows) ? t : (rows - 1);
    sidx[t] = idx[segStart + rowStart + r];
  }
  __syncthreads();   // the ONLY barrier: W1s + sidx visible to all waves

  int wr  = wave * 32;
  int l15 = lane & 15, lk = lane >> 4;

  // per-lane pre-swizzled A source pointers (m173: swizzle the SOURCE, LDS write linear)
  // stage inst i covers rows rl = i*8 + (lane>>3); LDS slot w = lane&7 holds
  // source 16B-unit (w ^ (rl&7)); rl&7 == lane>>3, so the XOR is i-independent.
  const char* srcp[4];
  {
    int sr = lane >> 3, w = lane & 7;
    int woff = (w ^ sr) * 16;
    #pragma unroll
    for (int i = 0; i < 4; ++i){
      int row = wr + i*8 + sr;
      int rc = (row < rows) ? row : (rows - 1);
      srcp[i] = reinterpret_cast<const char*>(x) + (size_t)sidx[rc]*1024 + woff;
    }
  }

  // stage one K-eighth (32 f32/row, 128B x 32 rows = 4KB) into wave's slice of buf q&3
  #define STAGE(q) { \
    char* db = Ab + ((q)&3)*16384 + wave*4096; \
    _Pragma("unroll") \
    for (int i = 0; i < 4; ++i){ \
      __builtin_amdgcn_global_load_lds( \
        (const __attribute__((address_space(1))) unsigned int*)(srcp[i] + (q)*128), \
        (__attribute__((address_space(3))) unsigned int*)(db + i*1024), \
        16, 0, 0); \
    } \
  }

  floatx4 acc[2][8];
  #pragma unroll
  for (int i = 0; i < 2; ++i)
    #pragma unroll
    for (int j = 0; j < 8; ++j) acc[i][j] = (floatx4)0.0f;

  STAGE(0); STAGE(1); STAGE(2);      // depth-3 prefetch

  int swz8 = l15 & 7;

  #pragma unroll
  for (int kf = 0; kf < 8; ++kf){
    if (kf < 5) STAGE(kf+3);
    // counted wait: ensure eighth kf landed; keep the 3 newer eighths in flight
    if (kf < 5)       asm volatile("s_waitcnt vmcnt(12)" ::: "memory");
    else if (kf == 5) asm volatile("s_waitcnt vmcnt(8)"  ::: "memory");
    else if (kf == 6) asm volatile("s_waitcnt vmcnt(4)"  ::: "memory");
    else              asm volatile("s_waitcnt vmcnt(0)"  ::: "memory");

    // B fragments from W1s (lgkm queue — never touches vmcnt)
    bf16x8 bf[8];
    #pragma unroll
    for (int nf = 0; nf < 8; ++nf)
      bf[nf] = *reinterpret_cast<const bf16x8*>(smem + (size_t)(nf*8 + kf)*1024 + lane*16);

    // A fragments from wave-private eighth buffer (swizzled read)
    bf16x8 af[2];
    #pragma unroll
    for (int mf = 0; mf < 2; ++mf){
      int rl = mf*16 + l15;
      const char* rb = Ab + (kf&3)*16384 + wave*4096 + rl*128;
      floatx4 f0 = *reinterpret_cast<const floatx4*>(rb + (((lk*2)   ^ swz8) * 16));
      floatx4 f1 = *reinterpret_cast<const floatx4*>(rb + (((lk*2+1) ^ swz8) * 16));
      uintx4 u;
      u[0] = f2bf2(f0[0], f0[1]); u[1] = f2bf2(f0[2], f0[3]);
      u[2] = f2bf2(f1[0], f1[1]); u[3] = f2bf2(f1[2], f1[3]);
      af[mf] = __builtin_bit_cast(bf16x8, u);
    }
    #pragma unroll
    for (int nf = 0; nf < 8; ++nf)
      acc[0][nf] = __builtin_amdgcn_mfma_f32_16x16x32_bf16(af[0], bf[nf], acc[0][nf], 0, 0, 0);
    #pragma unroll
    for (int nf = 0; nf < 8; ++nf)
      acc[1][nf] = __builtin_amdgcn_mfma_f32_16x16x32_bf16(af[1], bf[nf], acc[1][nf], 0, 0, 0);
  }

  // layer-1 epilogue: bias+relu -> bf16 hbuf in wave's OWN A-buf 0/1 slices (no barrier)
  #pragma unroll
  for (int nf = 0; nf < 8; ++nf){
    int col = nf*16 + l15;
    float bias = b1[c*HIDF + col];
    #pragma unroll
    for (int mf = 0; mf < 2; ++mf){
      #pragma unroll
      for (int j = 0; j < 4; ++j){
        int rl = mf*16 + lk*4 + j;
        float h = fmaxf(acc[mf][nf][j] + bias, 0.0f);
        int off = (rl>>4)*16384 + wave*4096 + (rl&15)*256 + ((col*2) ^ ((rl&7)<<4));
        *reinterpret_cast<unsigned short*>(Ab + off) = f2bf1(h);
      }
    }
  }

  // layer 2: [32 rows x 128] x [128 x 16(pad)]
  floatx4 acc2[2];
  acc2[0] = (floatx4)0.0f; acc2[1] = (floatx4)0.0f;
  const unsigned short* wb = W2p + (size_t)c*2048 + lane*8;
  #pragma unroll
  for (int kf = 0; kf < 4; ++kf){
    bf16x8 wv = *reinterpret_cast<const bf16x8*>(wb + kf*512);
    #pragma unroll
    for (int mf = 0; mf < 2; ++mf){
      int rl = mf*16 + l15;
      int off = (rl>>4)*16384 + wave*4096 + (rl&15)*256 + ((kf*64 + lk*16) ^ ((rl&7)<<4));
      bf16x8 av = *reinterpret_cast<const bf16x8*>(Ab + off);
      acc2[mf] = __builtin_amdgcn_mfma_f32_16x16x32_bf16(av, wv, acc2[mf], 0, 0, 0);
    }
  }

  int col = l15;
  if (col < OUTF){
    float bias2 = b2[c*OUTF + col];
    #pragma unroll
    for (int mf = 0; mf < 2; ++mf){
      #pragma unroll
      for (int j = 0; j < 4; ++j){
        int r = wr + mf*16 + lk*4 + j;
        if (r < rows)
          out[(size_t)sidx[r]*OUTF + col] = acc2[mf][j] + bias2;
      }
    }
  }
  #undef STAGE
}

extern "C" void kernel_launch(void* const* d_in, const int* in_sizes, int n_in,
                              void* d_out, int out_size, void* d_ws, size_t ws_size,
                              hipStream_t stream) {
  const float* x  = (const float*)d_in[0];
  const int*   cam= (const int*)d_in[1];
  const float* W1 = (const float*)d_in[2];
  const float* b1 = (const float*)d_in[3];
  const float* W2 = (const float*)d_in[4];
  const float* b2 = (const float*)d_in[5];
  float* out = (float*)d_out;

  char* ws = (char*)d_ws;
  int* counts     = (int*)(ws);          // 16 ints
  int* scatterOfs = (int*)(ws + 64);     // 16 ints
  int* idx        = (int*)(ws + 256);    // BB ints (1 MB)
  unsigned short* W1p = (unsigned short*)(ws + 256 + (size_t)BB*4);       // 983040 B
  unsigned short* W2p = W1p + (size_t)NCAM*8*8*64*8;                      // 61440 B

  (void)hipMemsetAsync(counts, 0, 128, stream);   // counts + scatterOfs
  hipLaunchKernelGGL(k_prephist, dim3(512),     dim3(256), 0, stream, W1, W2, cam, W1p, W2p, counts);
  hipLaunchKernelGGL(k_scatter,  dim3(BB/4096), dim3(256), 0, stream, cam, counts, scatterOfs, idx);
  hipLaunchKernelGGL(k_mlp,      dim3(MAXTILES),dim3(256), 0, stream,
                     x, idx, counts, W1p, W2p, b1, b2, out);
}

// Round 10
// 93.474 us; speedup vs baseline: 1.1484x; 1.1484x over previous
//
#include <hip/hip_runtime.h>
#include <hip/hip_bf16.h>

#define BB    262144
#define INF   256
#define HIDF  128
#define OUTF  15
#define NCAM  15
#define TM    128
#define MAXTILES (BB/TM + NCAM)   // 2063

typedef __attribute__((ext_vector_type(8))) short          bf16x8;
typedef __attribute__((ext_vector_type(4))) float          floatx4;
typedef __attribute__((ext_vector_type(4))) int            intx4;
typedef __attribute__((ext_vector_type(4))) unsigned int   uintx4;
typedef __attribute__((ext_vector_type(8))) unsigned short ushortx8;

__device__ __forceinline__ unsigned short f2bf1(float a){
  unsigned int u = __builtin_bit_cast(unsigned int, a);
  u += 0x7fffu + ((u >> 16) & 1u);          // round-to-nearest-even
  return (unsigned short)(u >> 16);
}
__device__ __forceinline__ unsigned int f2bf2(float a, float b){
  return (unsigned int)f2bf1(a) | ((unsigned int)f2bf1(b) << 16);
}

// ---------- fused prepack + histogram (counts/scatterOfs pre-zeroed by memset) ----------
__global__ void k_prephist(const float* __restrict__ W1, const float* __restrict__ W2,
                           const int* __restrict__ cam,
                           unsigned short* __restrict__ W1p, unsigned short* __restrict__ W2p,
                           int* __restrict__ counts){
  int bid = blockIdx.x, tid = threadIdx.x;
  if (bid < 240){
    int t = bid * 256 + tid;
    int l  = t & 63;
    int kf = (t >> 6) & 7;
    int nf = (t >> 9) & 7;
    int c  = t >> 12;
    int col = nf*16 + (l & 15);
    int k0  = kf*32 + (l >> 4)*8;
    ushortx8 v;
    #pragma unroll
    for (int j = 0; j < 8; ++j)
      v[j] = f2bf1(W1[((size_t)c*INF + k0 + j)*HIDF + col]);
    *reinterpret_cast<ushortx8*>(W1p + (size_t)t*8) = v;
  } else if (bid < 255){
    int c  = bid - 240;
    int l  = tid & 63;
    int kf = tid >> 6;            // 0..3
    int col = l & 15;
    int k0  = kf*32 + (l >> 4)*8;
    ushortx8 v;
    #pragma unroll
    for (int j = 0; j < 8; ++j){
      float f = (col < OUTF) ? W2[((size_t)c*HIDF + k0 + j)*OUTF + col] : 0.0f;
      v[j] = f2bf1(f);
    }
    *reinterpret_cast<ushortx8*>(W2p + ((size_t)(c*4 + kf)*64 + l)*8) = v;
  } else if (bid >= 256){
    __shared__ int lc[NCAM];
    if (tid < NCAM) lc[tid] = 0;
    __syncthreads();
    intx4 v = *reinterpret_cast<const intx4*>(cam + (size_t)((bid-256)*256 + tid)*4);
    atomicAdd(&lc[v[0]], 1); atomicAdd(&lc[v[1]], 1);
    atomicAdd(&lc[v[2]], 1); atomicAdd(&lc[v[3]], 1);
    __syncthreads();
    if (tid < NCAM && lc[tid]) atomicAdd(&counts[tid], lc[tid]);
  }
}

// ---------- scatter ----------
__global__ void k_scatter(const int* __restrict__ cam, const int* __restrict__ counts,
                          int* __restrict__ scatterOfs, int* __restrict__ idx){
  __shared__ int lc[NCAM];
  __shared__ int loff[NCAM];
  __shared__ int base[NCAM];
  int t = threadIdx.x;
  if (t < NCAM) lc[t] = 0;
  __syncthreads();
  int start = blockIdx.x * 4096;
  int camr[16], lpos[16];
  #pragma unroll
  for (int j = 0; j < 16; ++j){
    int i = start + j*256 + t;
    camr[j] = cam[i];
    lpos[j] = atomicAdd(&lc[camr[j]], 1);
  }
  __syncthreads();
  if (t == 0){
    int s = 0;
    #pragma unroll
    for (int c = 0; c < NCAM; ++c){ loff[c] = s; s += counts[c]; }
  }
  __syncthreads();
  if (t < NCAM) base[t] = loff[t] + atomicAdd(&scatterOfs[t], lc[t]);
  __syncthreads();
  #pragma unroll
  for (int j = 0; j < 16; ++j)
    idx[base[camr[j]] + lpos[j]] = start + j*256 + t;
}

// ---------- main fused MLP: zero-barrier, wave-private, counted-vmcnt pipeline ----------
// LDS 64KB: 4 ring slots x 16KB; per-wave slice 4KB (32 rows x 128B f32).
// hbuf (bf16, 8KB/wave) aliases the wave's slot0+slot1 slices after the K-loop.
// Swizzle (m173): source 16B-unit pre-XOR'd by row&7 at staging; reads XOR back.
__global__ __launch_bounds__(256, 2) void k_mlp(
    const float* __restrict__ x, const int* __restrict__ idx,
    const int* __restrict__ counts,
    const unsigned short* __restrict__ W1p, const unsigned short* __restrict__ W2p,
    const float* __restrict__ b1, const float* __restrict__ b2,
    float* __restrict__ out)
{
  __shared__ __align__(16) char smem[65536];

  int bid = blockIdx.x;
  // vectorized counts read: 4 parallel loads, then pure ALU mapping (the old
  // #pragma unroll 1 loop was 15 serial dependent L2/HBM loads = ~5us/block!)
  intx4 q0 = *reinterpret_cast<const intx4*>(counts);
  intx4 q1 = *reinterpret_cast<const intx4*>(counts + 4);
  intx4 q2 = *reinterpret_cast<const intx4*>(counts + 8);
  intx4 q3 = *reinterpret_cast<const intx4*>(counts + 12);
  int cnt[16] = {q0[0],q0[1],q0[2],q0[3], q1[0],q1[1],q1[2],q1[3],
                 q2[0],q2[1],q2[2],q2[3], q3[0],q3[1],q3[2],q3[3]};
  int c = -1, segStart = 0, rowStart = 0, rows = 0;
  {
    int cum = 0, rcum = 0;
    #pragma unroll
    for (int cc = 0; cc < NCAM; ++cc){
      int n  = cnt[cc];
      int nt = (n + TM - 1) >> 7;
      if (c < 0 && bid < cum + nt){
        c = cc;
        rowStart = (bid - cum) * TM;
        segStart = rcum;
        rows = n - rowStart; if (rows > TM) rows = TM;
      }
      cum += nt; rcum += n;
    }
  }
  if (c < 0) return;

  int t = threadIdx.x;
  int wave = t >> 6, lane = t & 63;
  int wr  = wave * 32, l15 = lane & 15, lk = lane >> 4;
  const int* idxBase = idx + segStart + rowStart;

  // per-lane pre-swizzled staging source pointers: stage inst i covers rows
  // i*8 + (lane>>3); lane's dst 16B-unit is lane&7, so source unit = (lane&7)^(row&7).
  const char* srcp[4];
  {
    int sr = lane >> 3, su = lane & 7;
    int woff = (su ^ sr) * 16;
    #pragma unroll
    for (int i = 0; i < 4; ++i){
      int row = wr + i*8 + sr;
      int rc = (row < rows) ? row : (rows - 1);
      srcp[i] = reinterpret_cast<const char*>(x) + (size_t)idxBase[rc]*1024 + woff;
    }
  }

  const unsigned short* bbase = W1p + (size_t)c*32768 + lane*8;

  // stage eighth qq (K-chunk of 32 f32/row) into wave's slice of slot qq&3
#define STAGE(qq) { \
    char* db = smem + ((qq)&3)*16384 + wave*4096; \
    _Pragma("unroll") \
    for (int i = 0; i < 4; ++i){ \
      __builtin_amdgcn_global_load_lds( \
        (const __attribute__((address_space(1))) unsigned int*)(srcp[i] + (qq)*128), \
        (__attribute__((address_space(3))) unsigned int*)(db + i*1024), \
        16, 0, 0); \
    } }

  floatx4 acc[2][8];
  #pragma unroll
  for (int i = 0; i < 2; ++i)
    #pragma unroll
    for (int j = 0; j < 8; ++j) acc[i][j] = (floatx4)0.0f;

  bf16x8 bfr[2][8];
  // prologue: B(0) [8 loads], then A eighths e0..e2 [12 stage insts]
  #pragma unroll
  for (int nf = 0; nf < 8; ++nf)
    bfr[0][nf] = *reinterpret_cast<const bf16x8*>(bbase + nf*4096);
  __builtin_amdgcn_sched_barrier(0);
  STAGE(0); STAGE(1); STAGE(2);
  __builtin_amdgcn_sched_barrier(0);

  int swz8 = l15 & 7;

  #pragma unroll
  for (int kf = 0; kf < 8; ++kf){
    // B prefetch (kf+1): 8 dwordx4 from L2
    if (kf < 7){
      #pragma unroll
      for (int nf = 0; nf < 8; ++nf)
        bfr[(kf+1)&1][nf] = *reinterpret_cast<const bf16x8*>(bbase + nf*4096 + (kf+1)*512);
    }
    __builtin_amdgcn_sched_barrier(0);
    if (kf < 5) STAGE(kf+3);
    __builtin_amdgcn_sched_barrier(0);
    // counted waits: A(e_kf) and B(kf) landed; 12-20 loads stay in flight
    if (kf == 0)      asm volatile("s_waitcnt vmcnt(20)" ::: "memory");
    else if (kf <= 4) asm volatile("s_waitcnt vmcnt(16)" ::: "memory");
    else if (kf == 5) asm volatile("s_waitcnt vmcnt(12)" ::: "memory");
    else if (kf == 6) asm volatile("s_waitcnt vmcnt(8)"  ::: "memory");
    else              asm volatile("s_waitcnt vmcnt(0)"  ::: "memory");
    __builtin_amdgcn_sched_barrier(0);

    // A fragments from wave-private slot (swizzled ds_read_b128), cvt to bf16
    bf16x8 af[2];
    #pragma unroll
    for (int mf = 0; mf < 2; ++mf){
      int rl = mf*16 + l15;
      const char* rb = smem + (kf&3)*16384 + wave*4096 + rl*128;
      floatx4 f0 = *reinterpret_cast<const floatx4*>(rb + (((2*lk)   ^ swz8) * 16));
      floatx4 f1 = *reinterpret_cast<const floatx4*>(rb + (((2*lk+1) ^ swz8) * 16));
      uintx4 u;
      u[0] = f2bf2(f0[0], f0[1]); u[1] = f2bf2(f0[2], f0[3]);
      u[2] = f2bf2(f1[0], f1[1]); u[3] = f2bf2(f1[2], f1[3]);
      af[mf] = __builtin_bit_cast(bf16x8, u);
    }
    #pragma unroll
    for (int nf = 0; nf < 8; ++nf)
      acc[0][nf] = __builtin_amdgcn_mfma_f32_16x16x32_bf16(af[0], bfr[kf&1][nf], acc[0][nf], 0, 0, 0);
    #pragma unroll
    for (int nf = 0; nf < 8; ++nf)
      acc[1][nf] = __builtin_amdgcn_mfma_f32_16x16x32_bf16(af[1], bfr[kf&1][nf], acc[1][nf], 0, 0, 0);
  }

  // layer-1 epilogue: bias+relu -> bf16 hbuf in wave's own slot0/1 slices (no barrier)
  #pragma unroll
  for (int nf = 0; nf < 8; ++nf){
    int col = nf*16 + l15;
    float bias = b1[c*HIDF + col];
    #pragma unroll
    for (int mf = 0; mf < 2; ++mf){
      #pragma unroll
      for (int j = 0; j < 4; ++j){
        int rl = mf*16 + lk*4 + j;
        float h = fmaxf(acc[mf][nf][j] + bias, 0.0f);
        int off = (rl>>4)*16384 + wave*4096 + (rl&15)*256 + ((col*2) ^ ((rl&7)<<4));
        *reinterpret_cast<unsigned short*>(smem + off) = f2bf1(h);
      }
    }
  }

  // layer 2: [32 rows x 128] x [128 x 16(pad)] — all wave-private
  floatx4 acc2[2];
  acc2[0] = (floatx4)0.0f; acc2[1] = (floatx4)0.0f;
  const unsigned short* wb = W2p + (size_t)c*2048 + lane*8;
  #pragma unroll
  for (int kf = 0; kf < 4; ++kf){
    bf16x8 wv = *reinterpret_cast<const bf16x8*>(wb + kf*512);
    #pragma unroll
    for (int mf = 0; mf < 2; ++mf){
      int rl = mf*16 + l15;
      int off = (rl>>4)*16384 + wave*4096 + (rl&15)*256 + ((kf*64 + lk*16) ^ ((rl&7)<<4));
      bf16x8 av = *reinterpret_cast<const bf16x8*>(smem + off);
      acc2[mf] = __builtin_amdgcn_mfma_f32_16x16x32_bf16(av, wv, acc2[mf], 0, 0, 0);
    }
  }

  int col = l15;
  if (col < OUTF){
    float bias2 = b2[c*OUTF + col];
    #pragma unroll
    for (int mf = 0; mf < 2; ++mf){
      #pragma unroll
      for (int j = 0; j < 4; ++j){
        int r = wr + mf*16 + lk*4 + j;
        if (r < rows)
          out[(size_t)idxBase[r]*OUTF + col] = acc2[mf][j] + bias2;
      }
    }
  }
#undef STAGE
}

extern "C" void kernel_launch(void* const* d_in, const int* in_sizes, int n_in,
                              void* d_out, int out_size, void* d_ws, size_t ws_size,
                              hipStream_t stream) {
  const float* x  = (const float*)d_in[0];
  const int*   cam= (const int*)d_in[1];
  const float* W1 = (const float*)d_in[2];
  const float* b1 = (const float*)d_in[3];
  const float* W2 = (const float*)d_in[4];
  const float* b2 = (const float*)d_in[5];
  float* out = (float*)d_out;

  char* ws = (char*)d_ws;
  int* counts     = (int*)(ws);          // 16 ints
  int* scatterOfs = (int*)(ws + 64);     // 16 ints
  int* idx        = (int*)(ws + 256);    // BB ints (1 MB)
  unsigned short* W1p = (unsigned short*)(ws + 256 + (size_t)BB*4);       // 983040 B
  unsigned short* W2p = W1p + (size_t)NCAM*8*8*64*8;                      // 61440 B

  (void)hipMemsetAsync(counts, 0, 128, stream);   // counts + scatterOfs
  hipLaunchKernelGGL(k_prephist, dim3(512),     dim3(256), 0, stream, W1, W2, cam, W1p, W2p, counts);
  hipLaunchKernelGGL(k_scatter,  dim3(BB/4096), dim3(256), 0, stream, cam, counts, scatterOfs, idx);
  hipLaunchKernelGGL(k_mlp,      dim3(MAXTILES),dim3(256), 0, stream,
                     x, idx, counts, W1p, W2p, b1, b2, out);
}